// Round 10
// baseline (335.950 us; speedup 1.0000x reference)
//
#include <hip/hip_runtime.h>
#include <math.h>

#define N4C 32768
#define N3C 65536
#define N2C 131072
#define N1C 262144

typedef _Float16 f16x8 __attribute__((ext_vector_type(8)));
typedef _Float16 f16x4 __attribute__((ext_vector_type(4)));
typedef float f32x4 __attribute__((ext_vector_type(4)));

__device__ __forceinline__ f32x4 mfma16(f16x8 a, f16x8 b, f32x4 c) {
  return __builtin_amdgcn_mfma_f32_16x16x32_f16(a, b, c, 0, 0, 0);
}

// fast celu: expm1(x) ~= __expf(x)-1 (v_exp_f32, abs err ~1e-7)
__device__ __forceinline__ float celuf(float x) {
  return x > 0.f ? x : (__expf(x) - 1.f);
}

// log_sigmoid(x) = min(x,0) - log(1 + exp(-|x|))
__device__ __forceinline__ float logsigf(float x) {
  float e = __expf(-fabsf(x));
  return fminf(x, 0.f) - __logf(1.f + e);
}

// ---------------------------------------------------------------------------
// Prep: z_mask [N4*64] f32 -> zf f16 (4 MB table; plain stores keep it L2-warm)
// ---------------------------------------------------------------------------
__global__ __launch_bounds__(256) void zhalf_kernel(const float* __restrict__ z,
                                                    _Float16* __restrict__ zf) {
  const int i = (blockIdx.x * 256 + threadIdx.x) * 4;
  float4 f = *(const float4*)(z + i);
  f16x4 h;
  h[0] = (_Float16)f.x; h[1] = (_Float16)f.y;
  h[2] = (_Float16)f.z; h[3] = (_Float16)f.w;
  *(f16x4*)(zf + i) = h;
}

// ---------------------------------------------------------------------------
// Level 3: PointConv (64 -> 64 -> 32), f16 MFMA, wave per point (16 edges = M).
// r8 skeleton. Branch-free rel: all quads compute it (their k rows are
// zero-masked in B; addresses dedupe across quads -> no extra cache lines).
// ---------------------------------------------------------------------------
__global__ __launch_bounds__(256) void l3_kernel(
    const _Float16* __restrict__ zf, const float* __restrict__ pos4,
    const float* __restrict__ pos3, const int* __restrict__ src3,
    const float* __restrict__ w1a, const float* __restrict__ b1a,
    const float* __restrict__ w1b, const float* __restrict__ b1b,
    _Float16* __restrict__ x3f) {
  __shared__ _Float16 hbuf[4][16 * 80];  // 160 B rows, 16B-aligned reads
  const int lane = threadIdx.x & 63;
  const int wid = threadIdx.x >> 6;
  const int col = lane & 15;   // MFMA n / A row m (edge)
  const int quad = lane >> 4;  // k-subchunk selector
  _Float16* hw = hbuf[wid];

  // B frags layer a: B[k][n], k = c*32 + quad*8 + j (K=67 pad 96), n = t*16+col
  f16x8 Ba[3][4];
#pragma unroll
  for (int c = 0; c < 3; ++c)
#pragma unroll
    for (int t = 0; t < 4; ++t)
#pragma unroll
      for (int j = 0; j < 8; ++j) {
        int k = c * 32 + quad * 8 + j;
        Ba[c][t][j] = (k < 67) ? (_Float16)w1a[k * 64 + t * 16 + col] : (_Float16)0.f;
      }
  f16x8 Bb[2][2];
#pragma unroll
  for (int c = 0; c < 2; ++c)
#pragma unroll
    for (int t = 0; t < 2; ++t)
#pragma unroll
      for (int j = 0; j < 8; ++j) {
        int k = c * 32 + quad * 8 + j;
        Bb[c][t][j] = (_Float16)w1b[k * 32 + t * 16 + col];
      }
  const float biasA0 = b1a[col], biasA1 = b1a[16 + col];
  const float biasA2 = b1a[32 + col], biasA3 = b1a[48 + col];
  const float biasB0 = b1b[col], biasB1 = b1b[16 + col];

  const int gwave = blockIdx.x * 4 + wid;
  const int nw = gridDim.x * 4;

  f16x8 A2 = {};  // j3..7 stay 0 (their k rows are zero-masked anyway)

  for (int p = gwave; p < N3C; p += nw) {
    const int s = __builtin_nontemporal_load(src3 + p * 16 + col);
    const int up = __builtin_amdgcn_readfirstlane(p);  // wave-uniform -> s_load
    const float po0 = pos3[up * 3 + 0];
    const float po1 = pos3[up * 3 + 1];
    const float po2 = pos3[up * 3 + 2];

    const _Float16* zr = zf + (size_t)s * 64;
    f16x8 A0 = *(const f16x8*)(zr + quad * 8);        // k 0..31
    f16x8 A1 = *(const f16x8*)(zr + 32 + quad * 8);   // k 32..63
    // rel on ALL quads (quad0: k64..66 real; others hit zero B rows).
    // pos4 addresses identical across quads -> coalesced, no extra lines.
    A2[0] = (_Float16)(pos4[s * 3 + 0] - po0);
    A2[1] = (_Float16)(pos4[s * 3 + 1] - po1);
    A2[2] = (_Float16)(pos4[s * 3 + 2] - po2);

    f32x4 d[4];
#pragma unroll
    for (int t = 0; t < 4; ++t) {
      f32x4 acc = {0.f, 0.f, 0.f, 0.f};
      acc = mfma16(A0, Ba[0][t], acc);
      acc = mfma16(A1, Ba[1][t], acc);
      acc = mfma16(A2, Ba[2][t], acc);
      d[t] = acc;
    }
    // C layout: row = quad*4 + r, col = n. celu -> f16 LDS [16][80].
#pragma unroll
    for (int r = 0; r < 4; ++r) {
      _Float16* bp = hw + (quad * 4 + r) * 80 + col;
      bp[0]  = (_Float16)celuf(d[0][r] + biasA0);
      bp[16] = (_Float16)celuf(d[1][r] + biasA1);
      bp[32] = (_Float16)celuf(d[2][r] + biasA2);
      bp[48] = (_Float16)celuf(d[3][r] + biasA3);
    }
    // same-wave LDS, in-order: no barrier. A'[m=col][k=c*32+quad*8+j]
    f16x8 P0 = *(const f16x8*)(hw + col * 80 + quad * 8);
    f16x8 P1 = *(const f16x8*)(hw + col * 80 + 32 + quad * 8);
    f32x4 e[2];
#pragma unroll
    for (int t = 0; t < 2; ++t) {
      f32x4 acc = {0.f, 0.f, 0.f, 0.f};
      acc = mfma16(P0, Bb[0][t], acc);
      acc = mfma16(P1, Bb[1][t], acc);
      e[t] = acc;
    }
    float m0 = fmaxf(fmaxf(e[0][0], e[0][1]), fmaxf(e[0][2], e[0][3]));
    float m1 = fmaxf(fmaxf(e[1][0], e[1][1]), fmaxf(e[1][2], e[1][3]));
    m0 = fmaxf(m0, __shfl_xor(m0, 16, 64));
    m0 = fmaxf(m0, __shfl_xor(m0, 32, 64));
    m1 = fmaxf(m1, __shfl_xor(m1, 16, 64));
    m1 = fmaxf(m1, __shfl_xor(m1, 32, 64));
    if (lane < 16) {
      _Float16* row = x3f + (size_t)p * 32;
      row[col]      = (_Float16)celuf(m0 + biasB0);  // max(x)+b == max(x+b)
      row[16 + col] = (_Float16)celuf(m1 + biasB1);
    }
  }
}

// ---------------------------------------------------------------------------
// Level 2: PointConv (32 -> 16 -> 16), f16 MFMA wave-per-point (r8 skeleton).
// Branch-free rel + branch-free P read (quads 2,3 alias quads 0,1: same LDS
// address -> broadcast; their k rows hit zero B).
// ---------------------------------------------------------------------------
__global__ __launch_bounds__(256) void l2_kernel(
    const _Float16* __restrict__ x3f, const float* __restrict__ pos3,
    const float* __restrict__ pos2, const int* __restrict__ src2,
    const float* __restrict__ w2a, const float* __restrict__ b2a,
    const float* __restrict__ w2b, const float* __restrict__ b2b,
    _Float16* __restrict__ x2f) {
  __shared__ _Float16 hbuf[4][16 * 24];  // 48 B rows, 16B-aligned reads
  const int lane = threadIdx.x & 63;
  const int wid = threadIdx.x >> 6;
  const int col = lane & 15;
  const int quad = lane >> 4;
  _Float16* hw = hbuf[wid];

  f16x8 Ba0, Ba1, Bb;
#pragma unroll
  for (int j = 0; j < 8; ++j) {
    int k = quad * 8 + j;
    Ba0[j] = (_Float16)w2a[k * 16 + col];                       // k 0..31
    Ba1[j] = (k + 32 < 35) ? (_Float16)w2a[(k + 32) * 16 + col] // k 32..34
                           : (_Float16)0.f;
    Bb[j] = (k < 16) ? (_Float16)w2b[k * 16 + col] : (_Float16)0.f;
  }
  const float biasA = b2a[col];
  const float biasB = b2b[col];

  const int gwave = blockIdx.x * 4 + wid;
  const int nw = gridDim.x * 4;

  f16x8 A1 = {};  // j3..7 stay 0 (zero-masked B rows)

  for (int p = gwave; p < N2C; p += nw) {
    const int s = __builtin_nontemporal_load(src2 + p * 16 + col);
    const int up = __builtin_amdgcn_readfirstlane(p);
    const float po0 = pos2[up * 3 + 0];
    const float po1 = pos2[up * 3 + 1];
    const float po2 = pos2[up * 3 + 2];

    f16x8 A0 = *(const f16x8*)(x3f + (size_t)s * 32 + quad * 8);  // k 0..31
    // rel on ALL quads (quad0: k32..34 real; others zero-masked in B).
    A1[0] = (_Float16)(pos3[s * 3 + 0] - po0);
    A1[1] = (_Float16)(pos3[s * 3 + 1] - po1);
    A1[2] = (_Float16)(pos3[s * 3 + 2] - po2);

    f32x4 d = {0.f, 0.f, 0.f, 0.f};
    d = mfma16(A0, Ba0, d);
    d = mfma16(A1, Ba1, d);
#pragma unroll
    for (int r = 0; r < 4; ++r)
      hw[(quad * 4 + r) * 24 + col] = (_Float16)celuf(d[r] + biasA);

    // P read on all quads: quads 2,3 read same address as 0,1 (broadcast);
    // their k 16..31 rows are zero in Bb.
    f16x8 P = *(const f16x8*)(hw + col * 24 + (quad & 1) * 8);
    f32x4 e = {0.f, 0.f, 0.f, 0.f};
    e = mfma16(P, Bb, e);

    float m0 = fmaxf(fmaxf(e[0], e[1]), fmaxf(e[2], e[3]));
    m0 = fmaxf(m0, __shfl_xor(m0, 16, 64));
    m0 = fmaxf(m0, __shfl_xor(m0, 32, 64));
    if (lane < 16) x2f[(size_t)p * 16 + col] = (_Float16)celuf(m0 + biasB);
  }
}

// ---------------------------------------------------------------------------
// Level 1: PointConv (16 -> 8 -> 8) + final linear + log_sigmoid (r8 skeleton).
// Branch-free LDS store (24-half rows: cols 8..15 land in pad), branch-free
// P read (all quads read the k0..7 segment; k>=8 rows zero in Bb).
// ---------------------------------------------------------------------------
__global__ __launch_bounds__(256) void l1_kernel(
    const _Float16* __restrict__ x2f, const float* __restrict__ pos2,
    const float* __restrict__ pos1, const int* __restrict__ src1,
    const float* __restrict__ w3a, const float* __restrict__ b3a,
    const float* __restrict__ w3b, const float* __restrict__ b3b,
    const float* __restrict__ wlin, const float* __restrict__ blin,
    float* __restrict__ out) {
  __shared__ _Float16 hbuf[4][16 * 24];  // 48 B rows, 16B-aligned, <=2-way banks
  const int lane = threadIdx.x & 63;
  const int wid = threadIdx.x >> 6;
  const int col = lane & 15;
  const int quad = lane >> 4;
  _Float16* hw = hbuf[wid];

  f16x8 Ba, Bb;
#pragma unroll
  for (int j = 0; j < 8; ++j) {
    int k = quad * 8 + j;
    Ba[j] = (k < 19 && col < 8) ? (_Float16)w3a[k * 8 + col] : (_Float16)0.f;
    Bb[j] = (k < 8 && col < 8) ? (_Float16)w3b[k * 8 + col] : (_Float16)0.f;
  }
  const float biasA = (col < 8) ? b3a[col] : 0.f;
  const float biasB = (col < 8) ? b3b[col] : 0.f;
  const float wl = (col < 8) ? wlin[col] : 0.f;
  const float bl = blin[0];

  const int gwave = blockIdx.x * 4 + wid;
  const int nw = gridDim.x * 4;

  for (int p = gwave; p < N1C; p += nw) {
    const int s = __builtin_nontemporal_load(src1 + p * 16 + col);
    const int up = __builtin_amdgcn_readfirstlane(p);
    const float po0 = pos1[up * 3 + 0];
    const float po1 = pos1[up * 3 + 1];
    const float po2 = pos1[up * 3 + 2];

    // A[m=col=edge][k=quad*8+j]: quads 0,1 = feat; quads 2,3 = rel.
    // quad3's k 24..31 rows are zero in Ba; addresses dedupe with quad2.
    f16x8 A;
    if (quad < 2) {
      A = *(const f16x8*)(x2f + (size_t)s * 16 + quad * 8);
    } else {
      f16x8 t = {};
      t[0] = (_Float16)(pos2[s * 3 + 0] - po0);
      t[1] = (_Float16)(pos2[s * 3 + 1] - po1);
      t[2] = (_Float16)(pos2[s * 3 + 2] - po2);
      A = t;
    }
    f32x4 d = {0.f, 0.f, 0.f, 0.f};
    d = mfma16(A, Ba, d);

    // Unconditional store: cols 8..15 write zero-weight garbage into pad.
#pragma unroll
    for (int r = 0; r < 4; ++r)
      hw[(quad * 4 + r) * 24 + col] = (_Float16)celuf(d[r] + biasA);

    // All quads read the k0..7 segment (same address -> broadcast; their
    // k>=8 rows are zero in Bb).
    f16x8 P = *(const f16x8*)(hw + col * 24);
    f32x4 e = {0.f, 0.f, 0.f, 0.f};
    e = mfma16(P, Bb, e);

    float m0 = fmaxf(fmaxf(e[0], e[1]), fmaxf(e[2], e[3]));
    m0 = fmaxf(m0, __shfl_xor(m0, 16, 64));
    m0 = fmaxf(m0, __shfl_xor(m0, 32, 64));
    // lane0 needs sum over cols 0..7 (cols 8..15 contribute 0): 3 shuffles
    float t = (col < 8) ? celuf(m0 + biasB) * wl : 0.f;
    t += __shfl_xor(t, 1, 64);
    t += __shfl_xor(t, 2, 64);
    t += __shfl_xor(t, 4, 64);
    if (lane == 0) out[p] = logsigf(t + bl);
  }
}

extern "C" void kernel_launch(void* const* d_in, const int* in_sizes, int n_in,
                              void* d_out, int out_size, void* d_ws, size_t ws_size,
                              hipStream_t stream) {
  const float* z_mask = (const float*)d_in[0];
  const float* pos4 = (const float*)d_in[1];
  const float* pos3 = (const float*)d_in[2];
  const float* pos2 = (const float*)d_in[3];
  const float* pos1 = (const float*)d_in[4];
  const float* w1a = (const float*)d_in[9];
  const float* b1a = (const float*)d_in[10];
  const float* w1b = (const float*)d_in[11];
  const float* b1b = (const float*)d_in[12];
  const float* w2a = (const float*)d_in[13];
  const float* b2a = (const float*)d_in[14];
  const float* w2b = (const float*)d_in[15];
  const float* b2b = (const float*)d_in[16];
  const float* w3a = (const float*)d_in[17];
  const float* b3a = (const float*)d_in[18];
  const float* w3b = (const float*)d_in[19];
  const float* b3b = (const float*)d_in[20];
  const float* wlin = (const float*)d_in[21];
  const float* blin = (const float*)d_in[22];
  const int* src3 = (const int*)d_in[23];
  const int* src2 = (const int*)d_in[25];
  const int* src1 = (const int*)d_in[27];

  // ws layout: [x3f 4 MB][regionB 4 MB]
  // regionB: zf (live prep..l3) then x2f (live l2..l1) — disjoint lifetimes.
  _Float16* x3f = (_Float16*)d_ws;                                 // [N3][32] f16
  _Float16* zf = (_Float16*)((char*)d_ws + (size_t)N3C * 32 * 2);  // [N4][64] f16
  _Float16* x2f = zf;                                              // [N2][16] f16
  float* out = (float*)d_out;

  zhalf_kernel<<<(N4C * 64) / (256 * 4), 256, 0, stream>>>(z_mask, zf);
  l3_kernel<<<2048, 256, 0, stream>>>(zf, pos4, pos3, src3, w1a, b1a, w1b, b1b, x3f);
  l2_kernel<<<8192, 256, 0, stream>>>(x3f, pos3, pos2, src2, w2a, b2a, w2b, b2b, x2f);
  l1_kernel<<<8192, 256, 0, stream>>>(x2f, pos2, pos1, src1, w3a, b3a, w3b, b3b,
                                      wlin, blin, out);
}

// Round 11
// 303.858 us; speedup vs baseline: 1.1056x; 1.1056x over previous
//
#include <hip/hip_runtime.h>
#include <hip/hip_fp16.h>
#include <math.h>

#define N4C 32768
#define N3C 65536
#define N2C 131072
#define N1C 262144

typedef _Float16 f16x8 __attribute__((ext_vector_type(8)));
typedef float f32x4 __attribute__((ext_vector_type(4)));

__device__ __forceinline__ f32x4 mfma16(f16x8 a, f16x8 b, f32x4 c) {
  return __builtin_amdgcn_mfma_f32_16x16x32_f16(a, b, c, 0, 0, 0);
}

// fast celu (f32): max(x,0) + expm1(min(x,0)), branch-free
__device__ __forceinline__ float celuf(float x) {
  return fmaxf(x, 0.f) + (__expf(fminf(x, 0.f)) - 1.f);
}

__device__ __forceinline__ float logsigf(float x) {
  float e = __expf(-fabsf(x));
  return fminf(x, 0.f) - __logf(1.f + e);
}

// f16 exp via hexp (ocml v_exp_f16 path)
__device__ __forceinline__ _Float16 exp16(_Float16 x) {
  __half h; __builtin_memcpy(&h, &x, 2);
  h = hexp(h);
  _Float16 r; __builtin_memcpy(&r, &h, 2);
  return r;
}

// packed celu on 8 halfs: max(x,0) + (exp(min(x,0)) - 1)
__device__ __forceinline__ f16x8 celu8(f16x8 x) {
  f16x8 z = {};
  f16x8 mx = __builtin_elementwise_max(x, z);
  f16x8 mn = __builtin_elementwise_min(x, z);
#pragma unroll
  for (int i = 0; i < 8; ++i) mn[i] = exp16(mn[i]);
  return mx + (mn - (_Float16)1.0f);
}

__device__ __forceinline__ unsigned packh2(_Float16 a, _Float16 b) {
  union { _Float16 h[2]; unsigned u; } v; v.h[0] = a; v.h[1] = b; return v.u;
}
__device__ __forceinline__ _Float16 loh(unsigned u) {
  union { unsigned u; _Float16 h[2]; } v; v.u = u; return v.h[0];
}
__device__ __forceinline__ _Float16 hih(unsigned u) {
  union { unsigned u; _Float16 h[2]; } v; v.u = u; return v.h[1];
}

// ---------------------------------------------------------------------------
// y4 = z @ W1a[:64] + b1a  (pre-activation, f16, [N4][64]) — dense GEMM,
// wave per 16 rows. Moves l3's layer-a off the gather path entirely.
// ---------------------------------------------------------------------------
__global__ __launch_bounds__(256) void y4_kernel(
    const float* __restrict__ z, const float* __restrict__ w1a,
    const float* __restrict__ b1a, _Float16* __restrict__ y4) {
  const int lane = threadIdx.x & 63, wid = threadIdx.x >> 6;
  const int col = lane & 15, quad = lane >> 4;
  const int base = (blockIdx.x * 4 + wid) * 16;

  f16x8 Ba[2][4];
#pragma unroll
  for (int c = 0; c < 2; ++c)
#pragma unroll
    for (int t = 0; t < 4; ++t)
#pragma unroll
      for (int j = 0; j < 8; ++j)
        Ba[c][t][j] = (_Float16)w1a[(c * 32 + quad * 8 + j) * 64 + t * 16 + col];

  const float* zr = z + (size_t)(base + col) * 64;
  f16x8 A0, A1;
  {
    float4 f0 = *(const float4*)(zr + quad * 8);
    float4 f1 = *(const float4*)(zr + quad * 8 + 4);
    float4 f2 = *(const float4*)(zr + 32 + quad * 8);
    float4 f3 = *(const float4*)(zr + 32 + quad * 8 + 4);
    A0[0] = (_Float16)f0.x; A0[1] = (_Float16)f0.y; A0[2] = (_Float16)f0.z; A0[3] = (_Float16)f0.w;
    A0[4] = (_Float16)f1.x; A0[5] = (_Float16)f1.y; A0[6] = (_Float16)f1.z; A0[7] = (_Float16)f1.w;
    A1[0] = (_Float16)f2.x; A1[1] = (_Float16)f2.y; A1[2] = (_Float16)f2.z; A1[3] = (_Float16)f2.w;
    A1[4] = (_Float16)f3.x; A1[5] = (_Float16)f3.y; A1[6] = (_Float16)f3.z; A1[7] = (_Float16)f3.w;
  }
#pragma unroll
  for (int t = 0; t < 4; ++t) {
    f32x4 acc = {0.f, 0.f, 0.f, 0.f};
    acc = mfma16(A0, Ba[0][t], acc);
    acc = mfma16(A1, Ba[1][t], acc);
    const float bt = b1a[t * 16 + col];
#pragma unroll
    for (int r = 0; r < 4; ++r)
      y4[(size_t)(base + quad * 4 + r) * 64 + t * 16 + col] = (_Float16)(acc[r] + bt);
  }
}

// ---------------------------------------------------------------------------
// y3 = x3 @ W2a[:32] + b2a  ([N3][16] f16) — halves l2's gather row to 32 B.
// ---------------------------------------------------------------------------
__global__ __launch_bounds__(256) void y3_kernel(
    const _Float16* __restrict__ x3f, const float* __restrict__ w2a,
    const float* __restrict__ b2a, _Float16* __restrict__ y3) {
  const int lane = threadIdx.x & 63, wid = threadIdx.x >> 6;
  const int col = lane & 15, quad = lane >> 4;
  const int base = (blockIdx.x * 4 + wid) * 16;

  f16x8 B;
#pragma unroll
  for (int j = 0; j < 8; ++j) B[j] = (_Float16)w2a[(quad * 8 + j) * 16 + col];

  f16x8 A = *(const f16x8*)(x3f + (size_t)(base + col) * 32 + quad * 8);
  f32x4 d = {0.f, 0.f, 0.f, 0.f};
  d = mfma16(A, B, d);
  const float bt = b2a[col];
#pragma unroll
  for (int r = 0; r < 4; ++r)
    y3[(size_t)(base + quad * 4 + r) * 16 + col] = (_Float16)(d[r] + bt);
}

// ---------------------------------------------------------------------------
// y2 = x2 @ W3a[:16] + b3a  ([N2][8] f16) — halves l1's gather row to 16 B.
// ---------------------------------------------------------------------------
__global__ __launch_bounds__(256) void y2_kernel(
    const _Float16* __restrict__ x2f, const float* __restrict__ w3a,
    const float* __restrict__ b3a, _Float16* __restrict__ y2) {
  const int lane = threadIdx.x & 63, wid = threadIdx.x >> 6;
  const int col = lane & 15, quad = lane >> 4;
  const int base = (blockIdx.x * 4 + wid) * 16;

  f16x8 B;
#pragma unroll
  for (int j = 0; j < 8; ++j) {
    int k = quad * 8 + j;
    B[j] = (k < 16 && col < 8) ? (_Float16)w3a[k * 8 + col] : (_Float16)0.f;
  }
  f16x8 A = *(const f16x8*)(x2f + (size_t)(base + col) * 16 + (quad & 1) * 8);
  f32x4 d = {0.f, 0.f, 0.f, 0.f};
  d = mfma16(A, B, d);
  if (col < 8) {
    const float bt = b3a[col];
#pragma unroll
    for (int r = 0; r < 4; ++r)
      y2[(size_t)(base + quad * 4 + r) * 8 + col] = (_Float16)(d[r] + bt);
  }
}

// ---------------------------------------------------------------------------
// Level 3 gather: h = celu(Y4[s] + rel@W1a[64:67]) in A-layout, layer-b MFMA,
// max-reduce. NO layer-a MFMA, NO LDS.
// ---------------------------------------------------------------------------
__global__ __launch_bounds__(256) void l3_kernel(
    const _Float16* __restrict__ y4, const float* __restrict__ pos4,
    const float* __restrict__ pos3, const int* __restrict__ src3,
    const float* __restrict__ w1a, const float* __restrict__ w1b,
    const float* __restrict__ b1b, _Float16* __restrict__ x3f) {
  const int lane = threadIdx.x & 63, wid = threadIdx.x >> 6;
  const int col = lane & 15, quad = lane >> 4;

  f16x8 Bb[2][2];
#pragma unroll
  for (int c = 0; c < 2; ++c)
#pragma unroll
    for (int t = 0; t < 2; ++t)
#pragma unroll
      for (int j = 0; j < 8; ++j)
        Bb[c][t][j] = (_Float16)w1b[(c * 32 + quad * 8 + j) * 32 + t * 16 + col];
  // rel weights W1a rows 64..66 in A-layout positions (ch = quad*8+j, +32)
  f16x8 W0[3], W1[3];
#pragma unroll
  for (int c = 0; c < 3; ++c)
#pragma unroll
    for (int j = 0; j < 8; ++j) {
      W0[c][j] = (_Float16)w1a[(64 + c) * 64 + quad * 8 + j];
      W1[c][j] = (_Float16)w1a[(64 + c) * 64 + 32 + quad * 8 + j];
    }
  const float biasB0 = b1b[col], biasB1 = b1b[16 + col];

  const int gwave = blockIdx.x * 4 + wid;
  const int nw = gridDim.x * 4;

  for (int p = gwave; p < N3C; p += nw) {
    const int s = src3[p * 16 + col];
    const int up = __builtin_amdgcn_readfirstlane(p);
    const float po0 = pos3[up * 3 + 0];
    const float po1 = pos3[up * 3 + 1];
    const float po2 = pos3[up * 3 + 2];

    f16x8 A0 = *(const f16x8*)(y4 + (size_t)s * 64 + quad * 8);
    f16x8 A1 = *(const f16x8*)(y4 + (size_t)s * 64 + 32 + quad * 8);

    // quad0 gathers pos4 & builds f16 rel; broadcast by col to all quads
    unsigned u0 = 0, u1 = 0;
    if (quad == 0) {
      _Float16 h0 = (_Float16)(pos4[s * 3 + 0] - po0);
      _Float16 h1 = (_Float16)(pos4[s * 3 + 1] - po1);
      _Float16 h2 = (_Float16)(pos4[s * 3 + 2] - po2);
      u0 = packh2(h0, h1);
      u1 = packh2(h2, (_Float16)0.f);
    }
    u0 = (unsigned)__shfl((int)u0, col, 64);
    u1 = (unsigned)__shfl((int)u1, col, 64);
    const _Float16 rr0 = loh(u0), rr1 = hih(u0), rr2 = loh(u1);

    A0 = celu8(A0 + W0[0] * rr0 + W0[1] * rr1 + W0[2] * rr2);
    A1 = celu8(A1 + W1[0] * rr0 + W1[1] * rr1 + W1[2] * rr2);

    f32x4 e[2];
#pragma unroll
    for (int t = 0; t < 2; ++t) {
      f32x4 acc = {0.f, 0.f, 0.f, 0.f};
      acc = mfma16(A0, Bb[0][t], acc);
      acc = mfma16(A1, Bb[1][t], acc);
      e[t] = acc;
    }
    float m0 = fmaxf(fmaxf(e[0][0], e[0][1]), fmaxf(e[0][2], e[0][3]));
    float m1 = fmaxf(fmaxf(e[1][0], e[1][1]), fmaxf(e[1][2], e[1][3]));
    m0 = fmaxf(m0, __shfl_xor(m0, 16, 64));
    m0 = fmaxf(m0, __shfl_xor(m0, 32, 64));
    m1 = fmaxf(m1, __shfl_xor(m1, 16, 64));
    m1 = fmaxf(m1, __shfl_xor(m1, 32, 64));
    if (lane < 16) {
      _Float16* row = x3f + (size_t)p * 32;
      row[col]      = (_Float16)celuf(m0 + biasB0);
      row[16 + col] = (_Float16)celuf(m1 + biasB1);
    }
  }
}

// ---------------------------------------------------------------------------
// Level 2 gather: h = celu(Y3[s] + rel@W2a[32:35]), 1 MFMA, max-reduce.
// Gather row = 32 B. NO LDS.
// ---------------------------------------------------------------------------
__global__ __launch_bounds__(256) void l2_kernel(
    const _Float16* __restrict__ y3, const float* __restrict__ pos3,
    const float* __restrict__ pos2, const int* __restrict__ src2,
    const float* __restrict__ w2a, const float* __restrict__ w2b,
    const float* __restrict__ b2b, _Float16* __restrict__ x2f) {
  const int lane = threadIdx.x & 63, wid = threadIdx.x >> 6;
  const int col = lane & 15, quad = lane >> 4;

  f16x8 Bb;
#pragma unroll
  for (int j = 0; j < 8; ++j) {
    int k = quad * 8 + j;
    Bb[j] = (k < 16) ? (_Float16)w2b[k * 16 + col] : (_Float16)0.f;
  }
  f16x8 W[3];
#pragma unroll
  for (int c = 0; c < 3; ++c)
#pragma unroll
    for (int j = 0; j < 8; ++j)
      W[c][j] = (quad < 2) ? (_Float16)w2a[(32 + c) * 16 + quad * 8 + j] : (_Float16)0.f;
  const float biasB = b2b[col];

  const int gwave = blockIdx.x * 4 + wid;
  const int nw = gridDim.x * 4;

  for (int p = gwave; p < N2C; p += nw) {
    const int s = src2[p * 16 + col];
    const int up = __builtin_amdgcn_readfirstlane(p);
    const float po0 = pos2[up * 3 + 0];
    const float po1 = pos2[up * 3 + 1];
    const float po2 = pos2[up * 3 + 2];

    f16x8 A = *(const f16x8*)(y3 + (size_t)s * 16 + (quad & 1) * 8);

    unsigned u0 = 0, u1 = 0;
    if (quad == 0) {
      _Float16 h0 = (_Float16)(pos3[s * 3 + 0] - po0);
      _Float16 h1 = (_Float16)(pos3[s * 3 + 1] - po1);
      _Float16 h2 = (_Float16)(pos3[s * 3 + 2] - po2);
      u0 = packh2(h0, h1);
      u1 = packh2(h2, (_Float16)0.f);
    }
    u0 = (unsigned)__shfl((int)u0, col, 64);
    u1 = (unsigned)__shfl((int)u1, col, 64);
    const _Float16 rr0 = loh(u0), rr1 = hih(u0), rr2 = loh(u1);

    A = celu8(A + W[0] * rr0 + W[1] * rr1 + W[2] * rr2);

    f32x4 e = {0.f, 0.f, 0.f, 0.f};
    e = mfma16(A, Bb, e);

    float m0 = fmaxf(fmaxf(e[0], e[1]), fmaxf(e[2], e[3]));
    m0 = fmaxf(m0, __shfl_xor(m0, 16, 64));
    m0 = fmaxf(m0, __shfl_xor(m0, 32, 64));
    if (lane < 16) x2f[(size_t)p * 16 + col] = (_Float16)celuf(m0 + biasB);
  }
}

// ---------------------------------------------------------------------------
// Level 1 gather: h = celu(Y2[s] + rel@W3a[16:19]), 1 MFMA, max-reduce,
// fused final linear + log_sigmoid. Gather row = 16 B. NO LDS.
// ---------------------------------------------------------------------------
__global__ __launch_bounds__(256) void l1_kernel(
    const _Float16* __restrict__ y2, const float* __restrict__ pos2,
    const float* __restrict__ pos1, const int* __restrict__ src1,
    const float* __restrict__ w3a, const float* __restrict__ w3b,
    const float* __restrict__ b3b, const float* __restrict__ wlin,
    const float* __restrict__ blin, float* __restrict__ out) {
  const int lane = threadIdx.x & 63, wid = threadIdx.x >> 6;
  const int col = lane & 15, quad = lane >> 4;

  f16x8 Bb;
#pragma unroll
  for (int j = 0; j < 8; ++j) {
    int k = quad * 8 + j;
    Bb[j] = (k < 8 && col < 8) ? (_Float16)w3b[k * 8 + col] : (_Float16)0.f;
  }
  f16x8 W[3];
#pragma unroll
  for (int c = 0; c < 3; ++c)
#pragma unroll
    for (int j = 0; j < 8; ++j)
      W[c][j] = (_Float16)w3a[(16 + c) * 8 + j];
  const float biasB = (col < 8) ? b3b[col] : 0.f;
  const float wl = (col < 8) ? wlin[col] : 0.f;
  const float bl = blin[0];

  const int gwave = blockIdx.x * 4 + wid;
  const int nw = gridDim.x * 4;

  for (int p = gwave; p < N1C; p += nw) {
    const int s = src1[p * 16 + col];
    const int up = __builtin_amdgcn_readfirstlane(p);
    const float po0 = pos1[up * 3 + 0];
    const float po1 = pos1[up * 3 + 1];
    const float po2 = pos1[up * 3 + 2];

    // whole 8-ch row in one 16-B load; same address across quads
    f16x8 A = *(const f16x8*)(y2 + (size_t)s * 8);

    // only quad0's k rows are live in Bb; other quads add rel*0
    _Float16 rr0 = (_Float16)0.f, rr1 = (_Float16)0.f, rr2 = (_Float16)0.f;
    if (quad == 0) {
      rr0 = (_Float16)(pos2[s * 3 + 0] - po0);
      rr1 = (_Float16)(pos2[s * 3 + 1] - po1);
      rr2 = (_Float16)(pos2[s * 3 + 2] - po2);
    }
    A = celu8(A + W[0] * rr0 + W[1] * rr1 + W[2] * rr2);

    f32x4 e = {0.f, 0.f, 0.f, 0.f};
    e = mfma16(A, Bb, e);

    float m0 = fmaxf(fmaxf(e[0], e[1]), fmaxf(e[2], e[3]));
    m0 = fmaxf(m0, __shfl_xor(m0, 16, 64));
    m0 = fmaxf(m0, __shfl_xor(m0, 32, 64));
    float t = (col < 8) ? celuf(m0 + biasB) * wl : 0.f;
    t += __shfl_xor(t, 1, 64);
    t += __shfl_xor(t, 2, 64);
    t += __shfl_xor(t, 4, 64);
    if (lane == 0) out[p] = logsigf(t + bl);
  }
}

extern "C" void kernel_launch(void* const* d_in, const int* in_sizes, int n_in,
                              void* d_out, int out_size, void* d_ws, size_t ws_size,
                              hipStream_t stream) {
  const float* z_mask = (const float*)d_in[0];
  const float* pos4 = (const float*)d_in[1];
  const float* pos3 = (const float*)d_in[2];
  const float* pos2 = (const float*)d_in[3];
  const float* pos1 = (const float*)d_in[4];
  const float* w1a = (const float*)d_in[9];
  const float* b1a = (const float*)d_in[10];
  const float* w1b = (const float*)d_in[11];
  const float* b1b = (const float*)d_in[12];
  const float* w2a = (const float*)d_in[13];
  const float* b2a = (const float*)d_in[14];
  const float* w2b = (const float*)d_in[15];
  const float* b2b = (const float*)d_in[16];
  const float* w3a = (const float*)d_in[17];
  const float* b3a = (const float*)d_in[18];
  const float* w3b = (const float*)d_in[19];
  const float* b3b = (const float*)d_in[20];
  const float* wlin = (const float*)d_in[21];
  const float* blin = (const float*)d_in[22];
  const int* src3 = (const int*)d_in[23];
  const int* src2 = (const int*)d_in[25];
  const int* src1 = (const int*)d_in[27];

  // ws (16 MB): Y4 4 | x3f 4 | Y3 2 | x2f 4 | Y2 2
  char* w = (char*)d_ws;
  _Float16* y4  = (_Float16*)(w);                      // [N4][64]
  _Float16* x3f = (_Float16*)(w + (4u << 20));         // [N3][32]
  _Float16* y3  = (_Float16*)(w + (8u << 20));         // [N3][16]
  _Float16* x2f = (_Float16*)(w + (10u << 20));        // [N2][16]
  _Float16* y2  = (_Float16*)(w + (14u << 20));        // [N2][8]
  float* out = (float*)d_out;

  y4_kernel<<<512, 256, 0, stream>>>(z_mask, w1a, b1a, y4);
  l3_kernel<<<2048, 256, 0, stream>>>(y4, pos4, pos3, src3, w1a, w1b, b1b, x3f);
  y3_kernel<<<1024, 256, 0, stream>>>(x3f, w2a, b2a, y3);
  l2_kernel<<<8192, 256, 0, stream>>>(y3, pos3, pos2, src2, w2a, w2b, b2b, x2f);
  y2_kernel<<<2048, 256, 0, stream>>>(x2f, w3a, b3a, y2);
  l1_kernel<<<8192, 256, 0, stream>>>(y2, pos2, pos1, src1, w3a, w3b, b3b,
                                      wlin, blin, out);
}

// Round 12
// 279.299 us; speedup vs baseline: 1.2028x; 1.0879x over previous
//
#include <hip/hip_runtime.h>
#include <hip/hip_fp16.h>
#include <math.h>

#define N4C 32768
#define N3C 65536
#define N2C 131072
#define N1C 262144

typedef _Float16 f16x8 __attribute__((ext_vector_type(8)));
typedef float f32x4 __attribute__((ext_vector_type(4)));
typedef float f32x16 __attribute__((ext_vector_type(16)));

__device__ __forceinline__ f32x4 mfma16(f16x8 a, f16x8 b, f32x4 c) {
  return __builtin_amdgcn_mfma_f32_16x16x32_f16(a, b, c, 0, 0, 0);
}
__device__ __forceinline__ f32x16 mfma32(f16x8 a, f16x8 b, f32x16 c) {
  return __builtin_amdgcn_mfma_f32_32x32x16_f16(a, b, c, 0, 0, 0);
}

// fast celu (f32): max(x,0) + expm1(min(x,0)), branch-free
__device__ __forceinline__ float celuf(float x) {
  return fmaxf(x, 0.f) + (__expf(fminf(x, 0.f)) - 1.f);
}

__device__ __forceinline__ float logsigf(float x) {
  float e = __expf(-fabsf(x));
  return fminf(x, 0.f) - __logf(1.f + e);
}

// f16 exp via hexp (ocml v_exp_f16 path)
__device__ __forceinline__ _Float16 exp16(_Float16 x) {
  __half h; __builtin_memcpy(&h, &x, 2);
  h = hexp(h);
  _Float16 r; __builtin_memcpy(&r, &h, 2);
  return r;
}

// packed celu on 8 halfs: max(x,0) + (exp(min(x,0)) - 1)
__device__ __forceinline__ f16x8 celu8(f16x8 x) {
  f16x8 z = {};
  f16x8 mx = __builtin_elementwise_max(x, z);
  f16x8 mn = __builtin_elementwise_min(x, z);
#pragma unroll
  for (int i = 0; i < 8; ++i) mn[i] = exp16(mn[i]);
  return mx + (mn - (_Float16)1.0f);
}

__device__ __forceinline__ unsigned packh2(_Float16 a, _Float16 b) {
  union { _Float16 h[2]; unsigned u; } v; v.h[0] = a; v.h[1] = b; return v.u;
}
__device__ __forceinline__ _Float16 loh(unsigned u) {
  union { unsigned u; _Float16 h[2]; } v; v.u = u; return v.h[0];
}
__device__ __forceinline__ _Float16 hih(unsigned u) {
  union { unsigned u; _Float16 h[2]; } v; v.u = u; return v.h[1];
}

// ---------------------------------------------------------------------------
// y4 = z @ W1a[:64] + b1a  ([N4][64] f16) — dense GEMM, wave per 16 rows.
// ---------------------------------------------------------------------------
__global__ __launch_bounds__(256) void y4_kernel(
    const float* __restrict__ z, const float* __restrict__ w1a,
    const float* __restrict__ b1a, _Float16* __restrict__ y4) {
  const int lane = threadIdx.x & 63, wid = threadIdx.x >> 6;
  const int col = lane & 15, quad = lane >> 4;
  const int base = (blockIdx.x * 4 + wid) * 16;

  f16x8 Ba[2][4];
#pragma unroll
  for (int c = 0; c < 2; ++c)
#pragma unroll
    for (int t = 0; t < 4; ++t)
#pragma unroll
      for (int j = 0; j < 8; ++j)
        Ba[c][t][j] = (_Float16)w1a[(c * 32 + quad * 8 + j) * 64 + t * 16 + col];

  const float* zr = z + (size_t)(base + col) * 64;
  f16x8 A0, A1;
  {
    float4 f0 = *(const float4*)(zr + quad * 8);
    float4 f1 = *(const float4*)(zr + quad * 8 + 4);
    float4 f2 = *(const float4*)(zr + 32 + quad * 8);
    float4 f3 = *(const float4*)(zr + 32 + quad * 8 + 4);
    A0[0] = (_Float16)f0.x; A0[1] = (_Float16)f0.y; A0[2] = (_Float16)f0.z; A0[3] = (_Float16)f0.w;
    A0[4] = (_Float16)f1.x; A0[5] = (_Float16)f1.y; A0[6] = (_Float16)f1.z; A0[7] = (_Float16)f1.w;
    A1[0] = (_Float16)f2.x; A1[1] = (_Float16)f2.y; A1[2] = (_Float16)f2.z; A1[3] = (_Float16)f2.w;
    A1[4] = (_Float16)f3.x; A1[5] = (_Float16)f3.y; A1[6] = (_Float16)f3.z; A1[7] = (_Float16)f3.w;
  }
#pragma unroll
  for (int t = 0; t < 4; ++t) {
    f32x4 acc = {0.f, 0.f, 0.f, 0.f};
    acc = mfma16(A0, Ba[0][t], acc);
    acc = mfma16(A1, Ba[1][t], acc);
    const float bt = b1a[t * 16 + col];
#pragma unroll
    for (int r = 0; r < 4; ++r)
      y4[(size_t)(base + quad * 4 + r) * 64 + t * 16 + col] = (_Float16)(acc[r] + bt);
  }
}

// ---------------------------------------------------------------------------
// y3 = x3 @ W2a[:32] + b2a  ([N3][16] f16)
// ---------------------------------------------------------------------------
__global__ __launch_bounds__(256) void y3_kernel(
    const _Float16* __restrict__ x3f, const float* __restrict__ w2a,
    const float* __restrict__ b2a, _Float16* __restrict__ y3) {
  const int lane = threadIdx.x & 63, wid = threadIdx.x >> 6;
  const int col = lane & 15, quad = lane >> 4;
  const int base = (blockIdx.x * 4 + wid) * 16;

  f16x8 B;
#pragma unroll
  for (int j = 0; j < 8; ++j) B[j] = (_Float16)w2a[(quad * 8 + j) * 16 + col];

  f16x8 A = *(const f16x8*)(x3f + (size_t)(base + col) * 32 + quad * 8);
  f32x4 d = {0.f, 0.f, 0.f, 0.f};
  d = mfma16(A, B, d);
  const float bt = b2a[col];
#pragma unroll
  for (int r = 0; r < 4; ++r)
    y3[(size_t)(base + quad * 4 + r) * 16 + col] = (_Float16)(d[r] + bt);
}

// ---------------------------------------------------------------------------
// y2 = x2 @ W3a[:16] + b3a  ([N2][8] f16)
// ---------------------------------------------------------------------------
__global__ __launch_bounds__(256) void y2_kernel(
    const _Float16* __restrict__ x2f, const float* __restrict__ w3a,
    const float* __restrict__ b3a, _Float16* __restrict__ y2) {
  const int lane = threadIdx.x & 63, wid = threadIdx.x >> 6;
  const int col = lane & 15, quad = lane >> 4;
  const int base = (blockIdx.x * 4 + wid) * 16;

  f16x8 B;
#pragma unroll
  for (int j = 0; j < 8; ++j) {
    int k = quad * 8 + j;
    B[j] = (k < 16 && col < 8) ? (_Float16)w3a[k * 8 + col] : (_Float16)0.f;
  }
  f16x8 A = *(const f16x8*)(x2f + (size_t)(base + col) * 16 + (quad & 1) * 8);
  f32x4 d = {0.f, 0.f, 0.f, 0.f};
  d = mfma16(A, B, d);
  if (col < 8) {
    const float bt = b3a[col];
#pragma unroll
    for (int r = 0; r < 4; ++r)
      y2[(size_t)(base + quad * 4 + r) * 8 + col] = (_Float16)(d[r] + bt);
  }
}

// ---------------------------------------------------------------------------
// Level 3 gather (r11 form, no lane redundancy): h = celu(Y4[s] + rel@W1a_rel),
// 4 MFMA, max-reduce. No LDS.
// ---------------------------------------------------------------------------
__global__ __launch_bounds__(256) void l3_kernel(
    const _Float16* __restrict__ y4, const float* __restrict__ pos4,
    const float* __restrict__ pos3, const int* __restrict__ src3,
    const float* __restrict__ w1a, const float* __restrict__ w1b,
    const float* __restrict__ b1b, _Float16* __restrict__ x3f) {
  const int lane = threadIdx.x & 63, wid = threadIdx.x >> 6;
  const int col = lane & 15, quad = lane >> 4;

  f16x8 Bb[2][2];
#pragma unroll
  for (int c = 0; c < 2; ++c)
#pragma unroll
    for (int t = 0; t < 2; ++t)
#pragma unroll
      for (int j = 0; j < 8; ++j)
        Bb[c][t][j] = (_Float16)w1b[(c * 32 + quad * 8 + j) * 32 + t * 16 + col];
  f16x8 W0[3], W1[3];
#pragma unroll
  for (int c = 0; c < 3; ++c)
#pragma unroll
    for (int j = 0; j < 8; ++j) {
      W0[c][j] = (_Float16)w1a[(64 + c) * 64 + quad * 8 + j];
      W1[c][j] = (_Float16)w1a[(64 + c) * 64 + 32 + quad * 8 + j];
    }
  const float biasB0 = b1b[col], biasB1 = b1b[16 + col];

  const int gwave = blockIdx.x * 4 + wid;
  const int nw = gridDim.x * 4;

  for (int p = gwave; p < N3C; p += nw) {
    const int s = src3[p * 16 + col];
    const int up = __builtin_amdgcn_readfirstlane(p);
    const float po0 = pos3[up * 3 + 0];
    const float po1 = pos3[up * 3 + 1];
    const float po2 = pos3[up * 3 + 2];

    f16x8 A0 = *(const f16x8*)(y4 + (size_t)s * 64 + quad * 8);
    f16x8 A1 = *(const f16x8*)(y4 + (size_t)s * 64 + 32 + quad * 8);

    unsigned u0 = 0, u1 = 0;
    if (quad == 0) {
      _Float16 h0 = (_Float16)(pos4[s * 3 + 0] - po0);
      _Float16 h1 = (_Float16)(pos4[s * 3 + 1] - po1);
      _Float16 h2 = (_Float16)(pos4[s * 3 + 2] - po2);
      u0 = packh2(h0, h1);
      u1 = packh2(h2, (_Float16)0.f);
    }
    u0 = (unsigned)__shfl((int)u0, col, 64);
    u1 = (unsigned)__shfl((int)u1, col, 64);
    const _Float16 rr0 = loh(u0), rr1 = hih(u0), rr2 = loh(u1);

    A0 = celu8(A0 + W0[0] * rr0 + W0[1] * rr1 + W0[2] * rr2);
    A1 = celu8(A1 + W1[0] * rr0 + W1[1] * rr1 + W1[2] * rr2);

    f32x4 e[2];
#pragma unroll
    for (int t = 0; t < 2; ++t) {
      f32x4 acc = {0.f, 0.f, 0.f, 0.f};
      acc = mfma16(A0, Bb[0][t], acc);
      acc = mfma16(A1, Bb[1][t], acc);
      e[t] = acc;
    }
    float m0 = fmaxf(fmaxf(e[0][0], e[0][1]), fmaxf(e[0][2], e[0][3]));
    float m1 = fmaxf(fmaxf(e[1][0], e[1][1]), fmaxf(e[1][2], e[1][3]));
    m0 = fmaxf(m0, __shfl_xor(m0, 16, 64));
    m0 = fmaxf(m0, __shfl_xor(m0, 32, 64));
    m1 = fmaxf(m1, __shfl_xor(m1, 16, 64));
    m1 = fmaxf(m1, __shfl_xor(m1, 32, 64));
    if (lane < 16) {
      _Float16* row = x3f + (size_t)p * 32;
      row[col]      = (_Float16)celuf(m0 + biasB0);
      row[16 + col] = (_Float16)celuf(m1 + biasB1);
    }
  }
}

// ---------------------------------------------------------------------------
// Level 2 gather: 2 points per wave via mfma_32x32x16 (m = 2x16 edges,
// k = 16 ch, n = 16 out ch). Zero lane redundancy.
// ---------------------------------------------------------------------------
__global__ __launch_bounds__(256) void l2_kernel(
    const _Float16* __restrict__ y3, const float* __restrict__ pos3,
    const float* __restrict__ pos2, const int* __restrict__ src2,
    const float* __restrict__ w2a, const float* __restrict__ w2b,
    const float* __restrict__ b2b, _Float16* __restrict__ x2f) {
  const int lane = threadIdx.x & 63, wid = threadIdx.x >> 6;
  const int n = lane & 31;        // MFMA col (out ch; <16 live)
  const int e = lane & 15;        // edge within point
  const int h = (lane >> 4) & 1;  // point within pair (m = e + 16*h)
  const int kh = lane >> 5;       // k-half (ch 0..7 / 8..15)

  f16x8 Bb;
#pragma unroll
  for (int j = 0; j < 8; ++j)
    Bb[j] = (n < 16) ? (_Float16)w2b[(kh * 8 + j) * 16 + n] : (_Float16)0.f;
  f16x8 W[3];
#pragma unroll
  for (int c = 0; c < 3; ++c)
#pragma unroll
    for (int j = 0; j < 8; ++j)
      W[c][j] = (_Float16)w2a[(32 + c) * 16 + kh * 8 + j];
  const float biasB = b2b[n & 15];

  const int gwave = blockIdx.x * 4 + wid;
  const int nw = gridDim.x * 4;

  for (int pr = gwave; pr < N2C / 2; pr += nw) {
    const int p = 2 * pr + h;
    const int s = src2[p * 16 + e];

    f16x8 A = *(const f16x8*)(y3 + (size_t)s * 16 + kh * 8);

    // rel on kh0 lanes (one per (e,h)); broadcast to kh1 partner
    unsigned u0 = 0, u1 = 0;
    if (kh == 0) {
      _Float16 h0 = (_Float16)(pos3[s * 3 + 0] - pos2[p * 3 + 0]);
      _Float16 h1 = (_Float16)(pos3[s * 3 + 1] - pos2[p * 3 + 1]);
      _Float16 h2 = (_Float16)(pos3[s * 3 + 2] - pos2[p * 3 + 2]);
      u0 = packh2(h0, h1);
      u1 = packh2(h2, (_Float16)0.f);
    }
    u0 = (unsigned)__shfl((int)u0, lane & 31, 64);
    u1 = (unsigned)__shfl((int)u1, lane & 31, 64);
    const _Float16 rr0 = loh(u0), rr1 = hih(u0), rr2 = loh(u1);

    A = celu8(A + W[0] * rr0 + W[1] * rr1 + W[2] * rr2);

    f32x16 acc = {};
    acc = mfma32(A, Bb, acc);

    // rows: regs 0..7 = point A (m 0..15), regs 8..15 = point B (m 16..31)
    float mA = acc[0], mB = acc[8];
#pragma unroll
    for (int r = 1; r < 8; ++r) {
      mA = fmaxf(mA, acc[r]);
      mB = fmaxf(mB, acc[8 + r]);
    }
    mA = fmaxf(mA, __shfl_xor(mA, 32, 64));
    mB = fmaxf(mB, __shfl_xor(mB, 32, 64));

    if (n < 16) {
      const float m = kh ? mB : mA;  // kh0 lanes (0..15) write A, kh1 (32..47) write B
      x2f[(size_t)(2 * pr + kh) * 16 + n] = (_Float16)celuf(m + biasB);
    }
  }
}

// ---------------------------------------------------------------------------
// Level 1 gather: 2 points per wave via mfma_32x32x16 (k 0..7 live, n 0..7
// live) + fused final linear + log_sigmoid. kh1 lanes carry zero A (B rows
// 8..15 are zero) and skip all gathers.
// ---------------------------------------------------------------------------
__global__ __launch_bounds__(256) void l1_kernel(
    const _Float16* __restrict__ y2, const float* __restrict__ pos2,
    const float* __restrict__ pos1, const int* __restrict__ src1,
    const float* __restrict__ w3a, const float* __restrict__ w3b,
    const float* __restrict__ b3b, const float* __restrict__ wlin,
    const float* __restrict__ blin, float* __restrict__ out) {
  const int lane = threadIdx.x & 63, wid = threadIdx.x >> 6;
  const int n = lane & 31;        // MFMA col (out ch; <8 live)
  const int e = lane & 15;        // edge
  const int h = (lane >> 4) & 1;  // point within pair
  const int kh = lane >> 5;       // k-half (only kh0 live)

  f16x8 Bb;
#pragma unroll
  for (int j = 0; j < 8; ++j)
    Bb[j] = (kh == 0 && n < 8) ? (_Float16)w3b[j * 8 + n] : (_Float16)0.f;
  f16x8 W[3];
#pragma unroll
  for (int c = 0; c < 3; ++c)
#pragma unroll
    for (int j = 0; j < 8; ++j)
      W[c][j] = (kh == 0) ? (_Float16)w3a[(16 + c) * 8 + j] : (_Float16)0.f;
  const float biasB = (n < 8) ? b3b[n] : 0.f;
  const float wl = (n < 8) ? wlin[n] : 0.f;
  const float bl = blin[0];

  const int gwave = blockIdx.x * 4 + wid;
  const int nw = gridDim.x * 4;

  for (int pr = gwave; pr < N1C / 2; pr += nw) {
    const int p = 2 * pr + h;

    f16x8 A = {};
    if (kh == 0) {  // only k 0..7 rows are live; kh1 lanes skip all gathers
      const int s = src1[p * 16 + e];
      A = *(const f16x8*)(y2 + (size_t)s * 8);
      const _Float16 rr0 = (_Float16)(pos2[s * 3 + 0] - pos1[p * 3 + 0]);
      const _Float16 rr1 = (_Float16)(pos2[s * 3 + 1] - pos1[p * 3 + 1]);
      const _Float16 rr2 = (_Float16)(pos2[s * 3 + 2] - pos1[p * 3 + 2]);
      A = celu8(A + W[0] * rr0 + W[1] * rr1 + W[2] * rr2);
    }

    f32x16 acc = {};
    acc = mfma32(A, Bb, acc);

    float mA = acc[0], mB = acc[8];
#pragma unroll
    for (int r = 1; r < 8; ++r) {
      mA = fmaxf(mA, acc[r]);
      mB = fmaxf(mB, acc[8 + r]);
    }
    mA = fmaxf(mA, __shfl_xor(mA, 32, 64));
    mB = fmaxf(mB, __shfl_xor(mB, 32, 64));

    // kh0 lanes do point A's epilogue, kh1 point B's
    const float m = kh ? mB : mA;
    float t = (n < 8) ? celuf(m + biasB) * wl : 0.f;
    t += __shfl_xor(t, 1, 64);
    t += __shfl_xor(t, 2, 64);
    t += __shfl_xor(t, 4, 64);
    if (n == 0) out[2 * pr + kh] = logsigf(t + bl);
  }
}

extern "C" void kernel_launch(void* const* d_in, const int* in_sizes, int n_in,
                              void* d_out, int out_size, void* d_ws, size_t ws_size,
                              hipStream_t stream) {
  const float* z_mask = (const float*)d_in[0];
  const float* pos4 = (const float*)d_in[1];
  const float* pos3 = (const float*)d_in[2];
  const float* pos2 = (const float*)d_in[3];
  const float* pos1 = (const float*)d_in[4];
  const float* w1a = (const float*)d_in[9];
  const float* b1a = (const float*)d_in[10];
  const float* w1b = (const float*)d_in[11];
  const float* b1b = (const float*)d_in[12];
  const float* w2a = (const float*)d_in[13];
  const float* b2a = (const float*)d_in[14];
  const float* w2b = (const float*)d_in[15];
  const float* b2b = (const float*)d_in[16];
  const float* w3a = (const float*)d_in[17];
  const float* b3a = (const float*)d_in[18];
  const float* w3b = (const float*)d_in[19];
  const float* b3b = (const float*)d_in[20];
  const float* wlin = (const float*)d_in[21];
  const float* blin = (const float*)d_in[22];
  const int* src3 = (const int*)d_in[23];
  const int* src2 = (const int*)d_in[25];
  const int* src1 = (const int*)d_in[27];

  // ws (16 MB): Y4 4 | x3f 4 | Y3 2 | x2f 4 | Y2 2
  char* w = (char*)d_ws;
  _Float16* y4  = (_Float16*)(w);                      // [N4][64]
  _Float16* x3f = (_Float16*)(w + (4u << 20));         // [N3][32]
  _Float16* y3  = (_Float16*)(w + (8u << 20));         // [N3][16]
  _Float16* x2f = (_Float16*)(w + (10u << 20));        // [N2][16]
  _Float16* y2  = (_Float16*)(w + (14u << 20));        // [N2][8]
  float* out = (float*)d_out;

  y4_kernel<<<512, 256, 0, stream>>>(z_mask, w1a, b1a, y4);
  l3_kernel<<<2048, 256, 0, stream>>>(y4, pos4, pos3, src3, w1a, w1b, b1b, x3f);
  y3_kernel<<<1024, 256, 0, stream>>>(x3f, w2a, b2a, y3);
  l2_kernel<<<8192, 256, 0, stream>>>(y3, pos3, pos2, src2, w2a, w2b, b2b, x2f);
  y2_kernel<<<2048, 256, 0, stream>>>(x2f, w3a, b3a, y2);
  l1_kernel<<<8192, 256, 0, stream>>>(y2, pos2, pos1, src1, w3a, w3b, b3b,
                                      wlin, blin, out);
}

// Round 13
// 271.578 us; speedup vs baseline: 1.2370x; 1.0284x over previous
//
#include <hip/hip_runtime.h>
#include <hip/hip_fp16.h>
#include <math.h>

#define N4C 32768
#define N3C 65536
#define N2C 131072
#define N1C 262144

typedef _Float16 f16x8 __attribute__((ext_vector_type(8)));
typedef float f32x4 __attribute__((ext_vector_type(4)));
typedef float f32x16 __attribute__((ext_vector_type(16)));

__device__ __forceinline__ f32x4 mfma16(f16x8 a, f16x8 b, f32x4 c) {
  return __builtin_amdgcn_mfma_f32_16x16x32_f16(a, b, c, 0, 0, 0);
}
__device__ __forceinline__ f32x16 mfma32(f16x8 a, f16x8 b, f32x16 c) {
  return __builtin_amdgcn_mfma_f32_32x32x16_f16(a, b, c, 0, 0, 0);
}

// fast celu (f32): max(x,0) + expm1(min(x,0)), branch-free
__device__ __forceinline__ float celuf(float x) {
  return fmaxf(x, 0.f) + (__expf(fminf(x, 0.f)) - 1.f);
}

__device__ __forceinline__ float logsigf(float x) {
  float e = __expf(-fabsf(x));
  return fminf(x, 0.f) - __logf(1.f + e);
}

// f16 exp via hexp (ocml v_exp_f16 path)
__device__ __forceinline__ _Float16 exp16(_Float16 x) {
  __half h; __builtin_memcpy(&h, &x, 2);
  h = hexp(h);
  _Float16 r; __builtin_memcpy(&r, &h, 2);
  return r;
}

// packed celu on 8 halfs: max(x,0) + (exp(min(x,0)) - 1)
__device__ __forceinline__ f16x8 celu8(f16x8 x) {
  f16x8 z = {};
  f16x8 mx = __builtin_elementwise_max(x, z);
  f16x8 mn = __builtin_elementwise_min(x, z);
#pragma unroll
  for (int i = 0; i < 8; ++i) mn[i] = exp16(mn[i]);
  return mx + (mn - (_Float16)1.0f);
}

__device__ __forceinline__ unsigned packh2(_Float16 a, _Float16 b) {
  union { _Float16 h[2]; unsigned u; } v; v.h[0] = a; v.h[1] = b; return v.u;
}
__device__ __forceinline__ _Float16 loh(unsigned u) {
  union { unsigned u; _Float16 h[2]; } v; v.u = u; return v.h[0];
}
__device__ __forceinline__ _Float16 hih(unsigned u) {
  union { unsigned u; _Float16 h[2]; } v; v.u = u; return v.h[1];
}

// ---------------------------------------------------------------------------
// y4 = z @ W1a[:64] + b1a  ([N4][64] f16) — dense GEMM, wave per 16 rows.
// ---------------------------------------------------------------------------
__global__ __launch_bounds__(256) void y4_kernel(
    const float* __restrict__ z, const float* __restrict__ w1a,
    const float* __restrict__ b1a, _Float16* __restrict__ y4) {
  const int lane = threadIdx.x & 63, wid = threadIdx.x >> 6;
  const int col = lane & 15, quad = lane >> 4;
  const int base = (blockIdx.x * 4 + wid) * 16;

  f16x8 Ba[2][4];
#pragma unroll
  for (int c = 0; c < 2; ++c)
#pragma unroll
    for (int t = 0; t < 4; ++t)
#pragma unroll
      for (int j = 0; j < 8; ++j)
        Ba[c][t][j] = (_Float16)w1a[(c * 32 + quad * 8 + j) * 64 + t * 16 + col];

  const float* zr = z + (size_t)(base + col) * 64;
  f16x8 A0, A1;
  {
    float4 f0 = *(const float4*)(zr + quad * 8);
    float4 f1 = *(const float4*)(zr + quad * 8 + 4);
    float4 f2 = *(const float4*)(zr + 32 + quad * 8);
    float4 f3 = *(const float4*)(zr + 32 + quad * 8 + 4);
    A0[0] = (_Float16)f0.x; A0[1] = (_Float16)f0.y; A0[2] = (_Float16)f0.z; A0[3] = (_Float16)f0.w;
    A0[4] = (_Float16)f1.x; A0[5] = (_Float16)f1.y; A0[6] = (_Float16)f1.z; A0[7] = (_Float16)f1.w;
    A1[0] = (_Float16)f2.x; A1[1] = (_Float16)f2.y; A1[2] = (_Float16)f2.z; A1[3] = (_Float16)f2.w;
    A1[4] = (_Float16)f3.x; A1[5] = (_Float16)f3.y; A1[6] = (_Float16)f3.z; A1[7] = (_Float16)f3.w;
  }
#pragma unroll
  for (int t = 0; t < 4; ++t) {
    f32x4 acc = {0.f, 0.f, 0.f, 0.f};
    acc = mfma16(A0, Ba[0][t], acc);
    acc = mfma16(A1, Ba[1][t], acc);
    const float bt = b1a[t * 16 + col];
#pragma unroll
    for (int r = 0; r < 4; ++r)
      y4[(size_t)(base + quad * 4 + r) * 64 + t * 16 + col] = (_Float16)(acc[r] + bt);
  }
}

// ---------------------------------------------------------------------------
// y3 = x3 @ W2a[:32] + b2a  ([N3][16] f16)
// ---------------------------------------------------------------------------
__global__ __launch_bounds__(256) void y3_kernel(
    const _Float16* __restrict__ x3f, const float* __restrict__ w2a,
    const float* __restrict__ b2a, _Float16* __restrict__ y3) {
  const int lane = threadIdx.x & 63, wid = threadIdx.x >> 6;
  const int col = lane & 15, quad = lane >> 4;
  const int base = (blockIdx.x * 4 + wid) * 16;

  f16x8 B;
#pragma unroll
  for (int j = 0; j < 8; ++j) B[j] = (_Float16)w2a[(quad * 8 + j) * 16 + col];

  f16x8 A = *(const f16x8*)(x3f + (size_t)(base + col) * 32 + quad * 8);
  f32x4 d = {0.f, 0.f, 0.f, 0.f};
  d = mfma16(A, B, d);
  const float bt = b2a[col];
#pragma unroll
  for (int r = 0; r < 4; ++r)
    y3[(size_t)(base + quad * 4 + r) * 16 + col] = (_Float16)(d[r] + bt);
}

// ---------------------------------------------------------------------------
// y2 = x2 @ W3a[:16] + b3a  ([N2][8] f16)
// ---------------------------------------------------------------------------
__global__ __launch_bounds__(256) void y2_kernel(
    const _Float16* __restrict__ x2f, const float* __restrict__ w3a,
    const float* __restrict__ b3a, _Float16* __restrict__ y2) {
  const int lane = threadIdx.x & 63, wid = threadIdx.x >> 6;
  const int col = lane & 15, quad = lane >> 4;
  const int base = (blockIdx.x * 4 + wid) * 16;

  f16x8 B;
#pragma unroll
  for (int j = 0; j < 8; ++j) {
    int k = quad * 8 + j;
    B[j] = (k < 16 && col < 8) ? (_Float16)w3a[k * 8 + col] : (_Float16)0.f;
  }
  f16x8 A = *(const f16x8*)(x2f + (size_t)(base + col) * 16 + (quad & 1) * 8);
  f32x4 d = {0.f, 0.f, 0.f, 0.f};
  d = mfma16(A, B, d);
  if (col < 8) {
    const float bt = b3a[col];
#pragma unroll
    for (int r = 0; r < 4; ++r)
      y2[(size_t)(base + quad * 4 + r) * 8 + col] = (_Float16)(d[r] + bt);
  }
}

// ---------------------------------------------------------------------------
// Level 3 gather (r11 form): h = celu(Y4[s] + rel@W1a_rel), 4 MFMA, max.
// ---------------------------------------------------------------------------
__global__ __launch_bounds__(256) void l3_kernel(
    const _Float16* __restrict__ y4, const float* __restrict__ pos4,
    const float* __restrict__ pos3, const int* __restrict__ src3,
    const float* __restrict__ w1a, const float* __restrict__ w1b,
    const float* __restrict__ b1b, _Float16* __restrict__ x3f) {
  const int lane = threadIdx.x & 63, wid = threadIdx.x >> 6;
  const int col = lane & 15, quad = lane >> 4;

  f16x8 Bb[2][2];
#pragma unroll
  for (int c = 0; c < 2; ++c)
#pragma unroll
    for (int t = 0; t < 2; ++t)
#pragma unroll
      for (int j = 0; j < 8; ++j)
        Bb[c][t][j] = (_Float16)w1b[(c * 32 + quad * 8 + j) * 32 + t * 16 + col];
  f16x8 W0[3], W1[3];
#pragma unroll
  for (int c = 0; c < 3; ++c)
#pragma unroll
    for (int j = 0; j < 8; ++j) {
      W0[c][j] = (_Float16)w1a[(64 + c) * 64 + quad * 8 + j];
      W1[c][j] = (_Float16)w1a[(64 + c) * 64 + 32 + quad * 8 + j];
    }
  const float biasB0 = b1b[col], biasB1 = b1b[16 + col];

  const int gwave = blockIdx.x * 4 + wid;
  const int nw = gridDim.x * 4;

  for (int p = gwave; p < N3C; p += nw) {
    const int s = src3[p * 16 + col];
    const int up = __builtin_amdgcn_readfirstlane(p);
    const float po0 = pos3[up * 3 + 0];
    const float po1 = pos3[up * 3 + 1];
    const float po2 = pos3[up * 3 + 2];

    f16x8 A0 = *(const f16x8*)(y4 + (size_t)s * 64 + quad * 8);
    f16x8 A1 = *(const f16x8*)(y4 + (size_t)s * 64 + 32 + quad * 8);

    unsigned u0 = 0, u1 = 0;
    if (quad == 0) {
      _Float16 h0 = (_Float16)(pos4[s * 3 + 0] - po0);
      _Float16 h1 = (_Float16)(pos4[s * 3 + 1] - po1);
      _Float16 h2 = (_Float16)(pos4[s * 3 + 2] - po2);
      u0 = packh2(h0, h1);
      u1 = packh2(h2, (_Float16)0.f);
    }
    u0 = (unsigned)__shfl((int)u0, col, 64);
    u1 = (unsigned)__shfl((int)u1, col, 64);
    const _Float16 rr0 = loh(u0), rr1 = hih(u0), rr2 = loh(u1);

    A0 = celu8(A0 + W0[0] * rr0 + W0[1] * rr1 + W0[2] * rr2);
    A1 = celu8(A1 + W1[0] * rr0 + W1[1] * rr1 + W1[2] * rr2);

    f32x4 e[2];
#pragma unroll
    for (int t = 0; t < 2; ++t) {
      f32x4 acc = {0.f, 0.f, 0.f, 0.f};
      acc = mfma16(A0, Bb[0][t], acc);
      acc = mfma16(A1, Bb[1][t], acc);
      e[t] = acc;
    }
    float m0 = fmaxf(fmaxf(e[0][0], e[0][1]), fmaxf(e[0][2], e[0][3]));
    float m1 = fmaxf(fmaxf(e[1][0], e[1][1]), fmaxf(e[1][2], e[1][3]));
    m0 = fmaxf(m0, __shfl_xor(m0, 16, 64));
    m0 = fmaxf(m0, __shfl_xor(m0, 32, 64));
    m1 = fmaxf(m1, __shfl_xor(m1, 16, 64));
    m1 = fmaxf(m1, __shfl_xor(m1, 32, 64));
    if (lane < 16) {
      _Float16* row = x3f + (size_t)p * 32;
      row[col]      = (_Float16)celuf(m0 + biasB0);
      row[16 + col] = (_Float16)celuf(m1 + biasB1);
    }
  }
}

// ---------------------------------------------------------------------------
// Level 2 gather: 2 points per wave via mfma_32x32x16 (unchanged from r12).
// ---------------------------------------------------------------------------
__global__ __launch_bounds__(256) void l2_kernel(
    const _Float16* __restrict__ y3, const float* __restrict__ pos3,
    const float* __restrict__ pos2, const int* __restrict__ src2,
    const float* __restrict__ w2a, const float* __restrict__ w2b,
    const float* __restrict__ b2b, _Float16* __restrict__ x2f) {
  const int lane = threadIdx.x & 63, wid = threadIdx.x >> 6;
  const int n = lane & 31;
  const int e = lane & 15;
  const int h = (lane >> 4) & 1;
  const int kh = lane >> 5;

  f16x8 Bb;
#pragma unroll
  for (int j = 0; j < 8; ++j)
    Bb[j] = (n < 16) ? (_Float16)w2b[(kh * 8 + j) * 16 + n] : (_Float16)0.f;
  f16x8 W[3];
#pragma unroll
  for (int c = 0; c < 3; ++c)
#pragma unroll
    for (int j = 0; j < 8; ++j)
      W[c][j] = (_Float16)w2a[(32 + c) * 16 + kh * 8 + j];
  const float biasB = b2b[n & 15];

  const int gwave = blockIdx.x * 4 + wid;
  const int nw = gridDim.x * 4;

  for (int pr = gwave; pr < N2C / 2; pr += nw) {
    const int p = 2 * pr + h;
    const int s = src2[p * 16 + e];

    f16x8 A = *(const f16x8*)(y3 + (size_t)s * 16 + kh * 8);

    unsigned u0 = 0, u1 = 0;
    if (kh == 0) {
      _Float16 h0 = (_Float16)(pos3[s * 3 + 0] - pos2[p * 3 + 0]);
      _Float16 h1 = (_Float16)(pos3[s * 3 + 1] - pos2[p * 3 + 1]);
      _Float16 h2 = (_Float16)(pos3[s * 3 + 2] - pos2[p * 3 + 2]);
      u0 = packh2(h0, h1);
      u1 = packh2(h2, (_Float16)0.f);
    }
    u0 = (unsigned)__shfl((int)u0, lane & 31, 64);
    u1 = (unsigned)__shfl((int)u1, lane & 31, 64);
    const _Float16 rr0 = loh(u0), rr1 = hih(u0), rr2 = loh(u1);

    A = celu8(A + W[0] * rr0 + W[1] * rr1 + W[2] * rr2);

    f32x16 acc = {};
    acc = mfma32(A, Bb, acc);

    float mA = acc[0], mB = acc[8];
#pragma unroll
    for (int r = 1; r < 8; ++r) {
      mA = fmaxf(mA, acc[r]);
      mB = fmaxf(mB, acc[8 + r]);
    }
    mA = fmaxf(mA, __shfl_xor(mA, 32, 64));
    mB = fmaxf(mB, __shfl_xor(mB, 32, 64));

    if (n < 16) {
      const float m = kh ? mB : mA;
      x2f[(size_t)(2 * pr + kh) * 16 + n] = (_Float16)celuf(m + biasB);
    }
  }
}

// ---------------------------------------------------------------------------
// Level 1 gather: 4 points per wave via block-diagonal mfma_32x32x16.
// B: k rows 0..7 = W3b for n 0..7, k rows 8..15 = W3b for n 8..15.
// A row m carries TWO points' h-vectors (one per k-half); 32 m-rows x 2
// k-halves = 4 points/MFMA. Every lane gathers one (point, edge) — zero
// dead lanes. src1 reads cover 64 consecutive indices (fully coalesced).
// ---------------------------------------------------------------------------
__global__ __launch_bounds__(256) void l1_kernel(
    const _Float16* __restrict__ y2, const float* __restrict__ pos2,
    const float* __restrict__ pos1, const int* __restrict__ src1,
    const float* __restrict__ w3a, const float* __restrict__ w3b,
    const float* __restrict__ b3b, const float* __restrict__ wlin,
    const float* __restrict__ blin, float* __restrict__ out) {
  const int lane = threadIdx.x & 63, wid = threadIdx.x >> 6;
  const int m = lane & 31;        // A row = edge + 16*h
  const int e = lane & 15;        // edge
  const int h = (lane >> 4) & 1;  // m-half point selector
  const int kh = lane >> 5;       // k-half point selector
  const int g = 2 * kh + h;       // point within quad (0..3)

  // B block-diagonal: live iff n<16 and (n>>3)==k-half; out-ch = n&7
  f16x8 Bb;
  const int n = m;  // B col index for this lane
#pragma unroll
  for (int j = 0; j < 8; ++j)
    Bb[j] = (n < 16 && (n >> 3) == kh) ? (_Float16)w3b[j * 8 + (n & 7)]
                                       : (_Float16)0.f;
  // rel weights: k-within-point = j for both k-halves
  f16x8 W[3];
#pragma unroll
  for (int c = 0; c < 3; ++c)
#pragma unroll
    for (int j = 0; j < 8; ++j)
      W[c][j] = (_Float16)w3a[(16 + c) * 8 + j];
  const float biasB = (n < 16) ? b3b[n & 7] : 0.f;
  const float wl = (n < 16) ? wlin[n & 7] : 0.f;
  const float bl = blin[0];

  const int gwave = blockIdx.x * 4 + wid;
  const int nw = gridDim.x * 4;

  for (int q = gwave; q < N1C / 4; q += nw) {
    const int pb = q * 4;
    const int p = pb + g;
    const int s = src1[p * 16 + e];  // lane->offset g*16+e: coalesced window

    f16x8 A = *(const f16x8*)(y2 + (size_t)s * 8);
    const _Float16 rr0 = (_Float16)(pos2[s * 3 + 0] - pos1[p * 3 + 0]);
    const _Float16 rr1 = (_Float16)(pos2[s * 3 + 1] - pos1[p * 3 + 1]);
    const _Float16 rr2 = (_Float16)(pos2[s * 3 + 2] - pos1[p * 3 + 2]);
    A = celu8(A + W[0] * rr0 + W[1] * rr1 + W[2] * rr2);

    f32x16 acc = {};
    acc = mfma32(A, Bb, acc);

    // regs 0..7 = m rows 0..15 (h=0 points), regs 8..15 = m 16..31 (h=1)
    float mA = acc[0], mB = acc[8];
#pragma unroll
    for (int r = 1; r < 8; ++r) {
      mA = fmaxf(mA, acc[r]);
      mB = fmaxf(mB, acc[8 + r]);
    }
    mA = fmaxf(mA, __shfl_xor(mA, 32, 64));
    mB = fmaxf(mB, __shfl_xor(mB, 32, 64));
    // col n<8: k-half-0 points (g = 0 via mA, 1 via mB)
    // col 8..15: k-half-1 points (g = 2 via mA, 3 via mB)
    float tA = celuf(mA + biasB) * wl;   // wl==0 for n>=16
    float tB = celuf(mB + biasB) * wl;
    tA += __shfl_xor(tA, 1, 64);
    tA += __shfl_xor(tA, 2, 64);
    tA += __shfl_xor(tA, 4, 64);
    tB += __shfl_xor(tB, 1, 64);
    tB += __shfl_xor(tB, 2, 64);
    tB += __shfl_xor(tB, 4, 64);
    if (lane == 0) {   // points 0 (mA) and 1 (mB)
      float2 o; o.x = logsigf(tA + bl); o.y = logsigf(tB + bl);
      *(float2*)(out + pb) = o;
    } else if (lane == 8) {  // points 2 (mA) and 3 (mB)
      float2 o; o.x = logsigf(tA + bl); o.y = logsigf(tB + bl);
      *(float2*)(out + pb + 2) = o;
    }
  }
}

extern "C" void kernel_launch(void* const* d_in, const int* in_sizes, int n_in,
                              void* d_out, int out_size, void* d_ws, size_t ws_size,
                              hipStream_t stream) {
  const float* z_mask = (const float*)d_in[0];
  const float* pos4 = (const float*)d_in[1];
  const float* pos3 = (const float*)d_in[2];
  const float* pos2 = (const float*)d_in[3];
  const float* pos1 = (const float*)d_in[4];
  const float* w1a = (const float*)d_in[9];
  const float* b1a = (const float*)d_in[10];
  const float* w1b = (const float*)d_in[11];
  const float* b1b = (const float*)d_in[12];
  const float* w2a = (const float*)d_in[13];
  const float* b2a = (const float*)d_in[14];
  const float* w2b = (const float*)d_in[15];
  const float* b2b = (const float*)d_in[16];
  const float* w3a = (const float*)d_in[17];
  const float* b3a = (const float*)d_in[18];
  const float* w3b = (const float*)d_in[19];
  const float* b3b = (const float*)d_in[20];
  const float* wlin = (const float*)d_in[21];
  const float* blin = (const float*)d_in[22];
  const int* src3 = (const int*)d_in[23];
  const int* src2 = (const int*)d_in[25];
  const int* src1 = (const int*)d_in[27];

  // ws (16 MB): Y4 4 | x3f 4 | Y3 2 | x2f 4 | Y2 2
  char* w = (char*)d_ws;
  _Float16* y4  = (_Float16*)(w);                      // [N4][64]
  _Float16* x3f = (_Float16*)(w + (4u << 20));         // [N3][32]
  _Float16* y3  = (_Float16*)(w + (8u << 20));         // [N3][16]
  _Float16* x2f = (_Float16*)(w + (10u << 20));        // [N2][16]
  _Float16* y2  = (_Float16*)(w + (14u << 20));        // [N2][8]
  float* out = (float*)d_out;

  y4_kernel<<<512, 256, 0, stream>>>(z_mask, w1a, b1a, y4);
  l3_kernel<<<2048, 256, 0, stream>>>(y4, pos4, pos3, src3, w1a, w1b, b1b, x3f);
  y3_kernel<<<1024, 256, 0, stream>>>(x3f, w2a, b2a, y3);
  l2_kernel<<<8192, 256, 0, stream>>>(y3, pos3, pos2, src2, w2a, w2b, b2b, x2f);
  y2_kernel<<<2048, 256, 0, stream>>>(x2f, w3a, b3a, y2);
  l1_kernel<<<8192, 256, 0, stream>>>(y2, pos2, pos1, src1, w3a, w3b, b3b,
                                      wlin, blin, out);
}